// Round 8
// baseline (944.406 us; speedup 1.0000x reference)
//
#include <hip/hip_runtime.h>
#include <hip/hip_bf16.h>
#include <stdint.h>
#include <stddef.h>

typedef __attribute__((ext_vector_type(8))) short short8;
typedef __attribute__((ext_vector_type(4))) short short4v;
typedef __attribute__((ext_vector_type(4))) float f32x4;

#define NB 2048
#define HD 512
#define SD 256

__device__ __forceinline__ short f2bf(float x) {
  __hip_bfloat16 h = __float2bfloat16(x);
  return *reinterpret_cast<short*>(&h);
}

__device__ __forceinline__ float fast_tanh(float x) {
  x = fminf(fmaxf(x, -15.f), 15.f);
  float e = __expf(2.f * x);
  return __fdividef(e - 1.f, e + 1.f);
}

// ---- Wtb[kb][j][kk] = bf16(W[kb*32+kk][j]) : k-blocked transposed layout ----
__global__ __launch_bounds__(256) void wconv_kernel(const float* __restrict__ W,
                                                    short* __restrict__ Wtb) {
  __shared__ float tile[32][33];
  const int bx = blockIdx.x;
  const int tk0 = (bx & 15) * 32;
  const int tj0 = (bx >> 4) * 32;
  const int lx = threadIdx.x & 31;
  const int ly = threadIdx.x >> 5;
  for (int r = 0; r < 4; ++r) {
    int yy = ly + r * 8;
    tile[yy][lx] = W[(size_t)(tk0 + yy) * HD + tj0 + lx];
  }
  __syncthreads();
  const int kb = tk0 >> 5;
  for (int r = 0; r < 4; ++r) {
    int yy = ly + r * 8;
    Wtb[(size_t)kb * (HD * 32) + (size_t)(tj0 + yy) * 32 + lx] = f2bf(tile[lx][yy]);
  }
}

// ---- alignment[n][s] = sum_j tanh( sum_k hs[n,k,s]*W[k,j] + b[j] ) * c[j] ----
// Block = 128 s x FULL 512 j (A read once). 1024 threads = 16 waves
// (2 s-halves x 8 j-strips of 64), wave tile 64s x 64j -> acc[4][4] = 64 VGPR
// -> ~116 total -> 4 waves/SIMD. BOTH A (8 KB bf16) and W (32 KB bf16) staged
// in LDS per 32-k step, double-buffered (80 KB). W L2 traffic: one fetch per
// block-step (2.1 GB total, was 16.8 GB per-wave). Stage issue placed before
// the MFMA cluster; pack/ds_write after it (loads covered by ~1240 cyc of
// MFMA per SIMD); single __syncthreads per step with an empty vmcnt drain.
__global__ void __launch_bounds__(1024, 4)
align_kernel(const float* __restrict__ hs, const short* __restrict__ Wtb,
             const float* __restrict__ bias, const float* __restrict__ ctxv,
             float* __restrict__ align_out)
{
  __shared__ short As[2][128 * 32];   // 8 KB per buffer
  __shared__ short Ws[2][512 * 32];   // 32 KB per buffer
  __shared__ float abuf[128];

  const int tid = threadIdx.x;
  const int n = blockIdx.x >> 1;
  const int s0 = (blockIdx.x & 1) * 128;
  const float* hsn = hs + (size_t)n * (HD * SD) + s0;

  if (tid < 128) abuf[tid] = 0.f;

  // A stage map: thread -> (s, k-quad): 4 k-strided fp32 -> short4 b64 write
  const int a_s = tid >> 3;            // 0..127
  const int a_o = (tid >> 1) & 3;      // k-octet 0..3
  const int a_h = tid & 1;             // k-quad within octet
  const int a_k = a_o * 8 + a_h * 4;
  // W stage map: thread -> (j, 2 octets): 2x short8 (32 B) global + b128 writes
  const int w_j = tid >> 1;            // 0..511
  const int w_o = (tid & 1) * 2;       // octets {0,1} or {2,3}

  // prologue: stage kt=0 into buffer 0
  {
    const float* src = hsn + (size_t)a_k * SD + a_s;
    short4v pk;
    #pragma unroll
    for (int e = 0; e < 4; ++e) pk[e] = f2bf(src[(size_t)e * SD]);
    *(short4v*)&As[0][a_s * 32 + a_k] = pk;

    const short* wsrc = Wtb + (size_t)w_j * 32 + w_o * 8;
    *(short8*)&Ws[0][w_j * 32 + w_o * 8] = *(const short8*)(wsrc);
    *(short8*)&Ws[0][w_j * 32 + w_o * 8 + 8] = *(const short8*)(wsrc + 8);
  }
  __syncthreads();

  const int lane = tid & 63;
  const int wid = tid >> 6;      // 0..15
  const int wm = wid >> 3;       // 0..1 : 64-s half
  const int wj = wid & 7;        // 0..7 : 64-j strip
  const int l15 = lane & 15;
  const int lg = lane >> 4;

  f32x4 acc[4][4];
  #pragma unroll
  for (int i = 0; i < 4; ++i)
    #pragma unroll
    for (int p = 0; p < 4; ++p)
      acc[i][p] = (f32x4){0.f, 0.f, 0.f, 0.f};

  const int aoff = (wm * 64 + l15) * 32 + lg * 8;   // + i*16*32
  const int woff = (wj * 64 + l15) * 32 + lg * 8;   // + p*16*32

  for (int kt = 0; kt < 16; ++kt) {
    const int cur = kt & 1;

    // 1) issue next-step global stage loads (A: 4 fp32, W: 2x short8)
    float av[4];
    short8 wv0, wv1;
    if (kt < 15) {
      const float* src = hsn + (size_t)((kt + 1) * 32 + a_k) * SD + a_s;
      #pragma unroll
      for (int e = 0; e < 4; ++e) av[e] = src[(size_t)e * SD];
      const short* wsrc = Wtb + (size_t)(kt + 1) * (HD * 32) + w_j * 32 + w_o * 8;
      wv0 = *(const short8*)(wsrc);
      wv1 = *(const short8*)(wsrc + 8);
    }

    // 2) W fragments from LDS (b128, even 8-slots/bank)
    short8 wf[4];
    #pragma unroll
    for (int p = 0; p < 4; ++p)
      wf[p] = *(const short8*)&Ws[cur][woff + p * (16 * 32)];

    // 3) MFMA: D[j][s] += Wfrag(16j x 32k) * Afrag(32k x 16s)
    #pragma unroll
    for (int i = 0; i < 4; ++i) {
      short8 af = *(const short8*)&As[cur][aoff + i * (16 * 32)];
      #pragma unroll
      for (int p = 0; p < 4; ++p)
        acc[i][p] = __builtin_amdgcn_mfma_f32_16x16x32_bf16(wf[p], af, acc[i][p], 0, 0, 0);
    }

    // 4) pack + LDS-write the prefetched tile into the other buffer
    if (kt < 15) {
      const int nxt = cur ^ 1;
      short4v pk;
      #pragma unroll
      for (int e = 0; e < 4; ++e) pk[e] = f2bf(av[e]);
      *(short4v*)&As[nxt][a_s * 32 + a_k] = pk;
      *(short8*)&Ws[nxt][w_j * 32 + w_o * 8] = wv0;
      *(short8*)&Ws[nxt][w_j * 32 + w_o * 8 + 8] = wv1;
    }
    __syncthreads();
  }

  // epilogue: D rows = j (lg*4 + r), cols = s (l15). tanh + *c, reduce j.
  float part[4] = {0.f, 0.f, 0.f, 0.f};
  #pragma unroll
  for (int p = 0; p < 4; ++p) {
    const int j = wj * 64 + p * 16 + lg * 4;
    f32x4 bv = *(const f32x4*)(bias + j);
    f32x4 cv = *(const f32x4*)(ctxv + j);
    #pragma unroll
    for (int i = 0; i < 4; ++i)
      #pragma unroll
      for (int r = 0; r < 4; ++r)
        part[i] += fast_tanh(acc[i][p][r] + bv[r]) * cv[r];
  }
  #pragma unroll
  for (int i = 0; i < 4; ++i) {
    part[i] += __shfl_xor(part[i], 16);
    part[i] += __shfl_xor(part[i], 32);
  }
  if (lg == 0) {
    #pragma unroll
    for (int i = 0; i < 4; ++i)
      atomicAdd(&abuf[wm * 64 + i * 16 + l15], part[i]);
  }
  __syncthreads();
  if (tid < 128) align_out[(size_t)n * SD + s0 + tid] = abuf[tid];
}

// ---- softmax over s + context[n,h] = sum_s attn[s]*hs[n,h,s] ----
__global__ __launch_bounds__(256) void ctx_kernel(const float* __restrict__ hs,
                                                  const float* __restrict__ align_in,
                                                  float* __restrict__ out)
{
  __shared__ __align__(16) float attn_s[256];
  __shared__ float red[8];
  const int n = blockIdx.x;
  const int t = threadIdx.x;
  const int lane = t & 63, wid = t >> 6;

  float a = align_in[(size_t)n * 256 + t];
  float m = a;
  #pragma unroll
  for (int off = 32; off; off >>= 1) m = fmaxf(m, __shfl_xor(m, off));
  if (lane == 0) red[wid] = m;
  __syncthreads();
  m = fmaxf(fmaxf(red[0], red[1]), fmaxf(red[2], red[3]));
  float e = __expf(a - m);
  float s = e;
  #pragma unroll
  for (int off = 32; off; off >>= 1) s += __shfl_xor(s, off);
  if (lane == 0) red[4 + wid] = s;
  __syncthreads();
  s = red[4] + red[5] + red[6] + red[7];
  attn_s[t] = e / s;
  __syncthreads();

  const int grp = t & 7;      // s-chunk of 32
  const int hrow = t >> 3;    // 0..31
  float av[32];
  #pragma unroll
  for (int u = 0; u < 8; ++u) {
    float4 v = *(const float4*)&attn_s[grp * 32 + u * 4];
    av[4*u+0] = v.x; av[4*u+1] = v.y; av[4*u+2] = v.z; av[4*u+3] = v.w;
  }
  const float* hb = hs + (size_t)n * (HD * SD) + grp * 32;
  for (int it = 0; it < 16; ++it) {
    const int h = it * 32 + hrow;
    const float4* p = (const float4*)(hb + (size_t)h * SD);
    float acc = 0.f;
    #pragma unroll
    for (int u = 0; u < 8; ++u) {
      float4 v = p[u];
      acc += av[4*u+0]*v.x + av[4*u+1]*v.y + av[4*u+2]*v.z + av[4*u+3]*v.w;
    }
    acc += __shfl_xor(acc, 1);
    acc += __shfl_xor(acc, 2);
    acc += __shfl_xor(acc, 4);
    if (grp == 0) out[(size_t)n * HD + h] = acc;
  }
}

extern "C" void kernel_launch(void* const* d_in, const int* in_sizes, int n_in,
                              void* d_out, int out_size, void* d_ws, size_t ws_size,
                              hipStream_t stream) {
  (void)in_sizes; (void)n_in; (void)out_size; (void)ws_size;
  const float* hs = (const float*)d_in[0];
  const float* W  = (const float*)d_in[1];
  const float* b  = (const float*)d_in[2];
  const float* c  = (const float*)d_in[3];
  float* out = (float*)d_out;

  float* align_ws = (float*)d_ws;                                  // 2 MB
  short* Wtb = (short*)((char*)d_ws + (size_t)NB * SD * 4);        // 512 KB

  wconv_kernel<<<256, 256, 0, stream>>>(W, Wtb);
  align_kernel<<<NB * 2, 1024, 0, stream>>>(hs, Wtb, b, c, align_ws);
  ctx_kernel<<<NB, 256, 0, stream>>>(hs, align_ws, out);
}